// Round 1
// baseline (2551.650 us; speedup 1.0000x reference)
//
#include <hip/hip_runtime.h>
#include <cstdint>
#include <cstddef>

static constexpr int NN = 100000;   // nodes
static constexpr int NE = 1600000;  // edges
static constexpr int NB = (NN + 255) / 256;  // 391 scan blocks

// ---------------- degree histogram ----------------
__global__ __launch_bounds__(256) void k_hist(const int* __restrict__ src, const int* __restrict__ dst,
                                              int* __restrict__ cnt_out, int* __restrict__ cnt_in) {
    int e = blockIdx.x * 256 + threadIdx.x;
    if (e < NE) {
        atomicAdd(&cnt_out[src[e]], 1);
        atomicAdd(&cnt_in[dst[e]], 1);
    }
}

__global__ __launch_bounds__(256) void k_deg(const int* __restrict__ cnt_out, const int* __restrict__ cnt_in,
                                             float* __restrict__ dout, float* __restrict__ din) {
    int i = blockIdx.x * 256 + threadIdx.x;
    if (i < NN) {
        dout[i] = rsqrtf(fmaxf((float)cnt_out[i], 1.0f));
        din[i]  = rsqrtf(fmaxf((float)cnt_in[i], 1.0f));
    }
}

// ---------------- 3-kernel exclusive scan of cnt_in -> row_start ----------------
__global__ __launch_bounds__(256) void k_scan1(const int* __restrict__ cnt, int* __restrict__ excl,
                                               int* __restrict__ bsum) {
    __shared__ int sd[256];
    int i = blockIdx.x * 256 + threadIdx.x;
    int v = (i < NN) ? cnt[i] : 0;
    sd[threadIdx.x] = v;
    __syncthreads();
    #pragma unroll
    for (int off = 1; off < 256; off <<= 1) {
        int t = (threadIdx.x >= off) ? sd[threadIdx.x - off] : 0;
        __syncthreads();
        sd[threadIdx.x] += t;
        __syncthreads();
    }
    if (i < NN) excl[i] = sd[threadIdx.x] - v;       // exclusive within block
    if (threadIdx.x == 255) bsum[blockIdx.x] = sd[255];
}

__global__ __launch_bounds__(512) void k_scan2(const int* __restrict__ bsum, int* __restrict__ boff, int nb) {
    __shared__ int sd[512];
    int v = ((int)threadIdx.x < nb) ? bsum[threadIdx.x] : 0;
    sd[threadIdx.x] = v;
    __syncthreads();
    #pragma unroll
    for (int off = 1; off < 512; off <<= 1) {
        int t = (threadIdx.x >= off) ? sd[threadIdx.x - off] : 0;
        __syncthreads();
        sd[threadIdx.x] += t;
        __syncthreads();
    }
    if ((int)threadIdx.x < nb) boff[threadIdx.x] = sd[threadIdx.x] - v;  // exclusive
}

__global__ __launch_bounds__(256) void k_scan3(int* __restrict__ row_start, int* __restrict__ cursor,
                                               const int* __restrict__ boff) {
    int i = blockIdx.x * 256 + threadIdx.x;
    if (i < NN) {
        int rs = row_start[i] + boff[blockIdx.x];
        row_start[i] = rs;
        cursor[i] = rs;
    }
    if (i == 0) row_start[NN] = NE;
}

// ---------------- counting-sort edges by dst ----------------
__global__ __launch_bounds__(256) void k_scatter(const int* __restrict__ src, const int* __restrict__ dst,
                                                 int* __restrict__ cursor, int* __restrict__ edge_src) {
    int e = blockIdx.x * 256 + threadIdx.x;
    if (e < NE) {
        int p = atomicAdd(&cursor[dst[e]], 1);
        edge_src[p] = src[e];
    }
}

// ---------------- pull aggregation: one wave per dst node ----------------
// out[n] = sum_{e: dst==n} deg_out_inv[src_e] * x[src_e]
// FINAL: out[n] = (acc + bias) * deg_in_inv[n]  (layer-3 epilogue, writes d_out)
template <int D, bool FINAL>
__global__ __launch_bounds__(256) void k_agg(const float* __restrict__ x, const int* __restrict__ edge_src,
                                             const int* __restrict__ row_start,
                                             const float* __restrict__ deg_out_inv,
                                             const float* __restrict__ deg_in_inv,
                                             const float* __restrict__ bias,
                                             float* __restrict__ out) {
    constexpr int VEC = D / 64;  // 2 for D=128, 4 for D=256
    int node = blockIdx.x * 4 + (threadIdx.x >> 6);
    int lane = threadIdx.x & 63;
    int beg = row_start[node];
    int end = row_start[node + 1];
    float acc[VEC];
    #pragma unroll
    for (int v = 0; v < VEC; ++v) acc[v] = 0.0f;
    const float* xb = x + (size_t)lane * VEC;
    if (beg < end) {
        int s_next = edge_src[beg];
        for (int i = beg; i < end; ++i) {
            int s = s_next;
            s_next = edge_src[min(i + 1, end - 1)];   // prefetch next edge id
            float w = deg_out_inv[s];
            if constexpr (VEC == 4) {
                float4 val = *(const float4*)(xb + (size_t)s * D);
                acc[0] = fmaf(w, val.x, acc[0]);
                acc[1] = fmaf(w, val.y, acc[1]);
                acc[2] = fmaf(w, val.z, acc[2]);
                acc[3] = fmaf(w, val.w, acc[3]);
            } else {
                float2 val = *(const float2*)(xb + (size_t)s * D);
                acc[0] = fmaf(w, val.x, acc[0]);
                acc[1] = fmaf(w, val.y, acc[1]);
            }
        }
    }
    float* o = out + (size_t)node * D + lane * VEC;
    if constexpr (FINAL) {
        float dv = deg_in_inv[node];
        #pragma unroll
        for (int v = 0; v < VEC; ++v) o[v] = (acc[v] + bias[lane * VEC + v]) * dv;
    } else {
        #pragma unroll
        for (int v = 0; v < VEC; ++v) o[v] = acc[v];
    }
}

// ---------------- fp32 GEMM: out[N x M] = A[N x K] @ W[K x M] (+bias)*deg_in ----------------
// Block: 256 threads, 16 rows. A-row addresses are block-uniform -> scalar loads.
template <int K, int M, bool EPI>
__global__ __launch_bounds__(256) void k_gemm(const float* __restrict__ A, const float* __restrict__ W,
                                              const float* __restrict__ bias,
                                              const float* __restrict__ deg_in_inv,
                                              float* __restrict__ out) {
    constexpr int GROUPS = 256 / M;     // 1 for M=256, 2 for M=128
    constexpr int RT = 16 / GROUPS;     // rows per thread
    int c = threadIdx.x % M;
    int g = threadIdx.x / M;
    int r0 = blockIdx.x * 16 + g * RT;
    float acc[RT];
    #pragma unroll
    for (int r = 0; r < RT; ++r) acc[r] = 0.0f;
    for (int k = 0; k < K; k += 4) {
        float w0 = W[(size_t)(k + 0) * M + c];
        float w1 = W[(size_t)(k + 1) * M + c];
        float w2 = W[(size_t)(k + 2) * M + c];
        float w3 = W[(size_t)(k + 3) * M + c];
        #pragma unroll
        for (int r = 0; r < RT; ++r) {
            float4 a = *(const float4*)(A + (size_t)(r0 + r) * K + k);
            acc[r] = fmaf(a.x, w0, acc[r]);
            acc[r] = fmaf(a.y, w1, acc[r]);
            acc[r] = fmaf(a.z, w2, acc[r]);
            acc[r] = fmaf(a.w, w3, acc[r]);
        }
    }
    #pragma unroll
    for (int r = 0; r < RT; ++r) {
        float v = acc[r];
        if constexpr (EPI) v = (v + bias[c]) * deg_in_inv[r0 + r];
        out[(size_t)(r0 + r) * M + c] = v;
    }
}

// ---------------- LayerNorm + PReLU, in place, one wave per row (D=256) ----------------
__global__ __launch_bounds__(256) void k_ln(float* __restrict__ h, const float* __restrict__ g,
                                            const float* __restrict__ be, const float* __restrict__ a) {
    int row = blockIdx.x * 4 + (threadIdx.x >> 6);
    int lane = threadIdx.x & 63;
    float* p = h + (size_t)row * 256 + lane * 4;
    float4 v = *(const float4*)p;
    float s = v.x + v.y + v.z + v.w;
    float q = v.x * v.x + v.y * v.y + v.z * v.z + v.w * v.w;
    #pragma unroll
    for (int off = 32; off > 0; off >>= 1) {
        s += __shfl_down(s, off);
        q += __shfl_down(q, off);
    }
    s = __shfl(s, 0);
    q = __shfl(q, 0);
    float mu = s * (1.0f / 256.0f);
    float var = q * (1.0f / 256.0f) - mu * mu;
    float rs = rsqrtf(var + 1e-5f);
    float alpha = a[0];
    float4 gv = *(const float4*)(g + lane * 4);
    float4 bv = *(const float4*)(be + lane * 4);
    float o0 = gv.x * (v.x - mu) * rs + bv.x; o0 = (o0 >= 0.0f) ? o0 : alpha * o0;
    float o1 = gv.y * (v.y - mu) * rs + bv.y; o1 = (o1 >= 0.0f) ? o1 : alpha * o1;
    float o2 = gv.z * (v.z - mu) * rs + bv.z; o2 = (o2 >= 0.0f) ? o2 : alpha * o2;
    float o3 = gv.w * (v.w - mu) * rs + bv.w; o3 = (o3 >= 0.0f) ? o3 : alpha * o3;
    *(float4*)p = make_float4(o0, o1, o2, o3);
}

extern "C" void kernel_launch(void* const* d_in, const int* in_sizes, int n_in,
                              void* d_out, int out_size, void* d_ws, size_t ws_size,
                              hipStream_t stream) {
    const float* feat = (const float*)d_in[0];
    const float* W1 = (const float*)d_in[1];
    const float* b1 = (const float*)d_in[2];
    const float* g1 = (const float*)d_in[3];
    const float* be1 = (const float*)d_in[4];
    const float* a1 = (const float*)d_in[5];
    const float* W2 = (const float*)d_in[6];
    const float* b2 = (const float*)d_in[7];
    const float* g2 = (const float*)d_in[8];
    const float* be2 = (const float*)d_in[9];
    const float* a2 = (const float*)d_in[10];
    const float* W3 = (const float*)d_in[11];
    const float* b3 = (const float*)d_in[12];
    const int* src = (const int*)d_in[13];
    const int* dst = (const int*)d_in[14];

    char* ws = (char*)d_ws;
    size_t off = 0;
    auto alloc = [&](size_t bytes) -> void* {
        off = (off + 511) & ~(size_t)511;
        void* p = ws + off;
        off += bytes;
        return p;
    };
    int* cnt_out = (int*)alloc((size_t)NN * 4);
    int* cnt_in = (int*)alloc((size_t)NN * 4);
    float* deg_out_inv = (float*)alloc((size_t)NN * 4);
    float* deg_in_inv = (float*)alloc((size_t)NN * 4);
    int* row_start = (int*)alloc((size_t)(NN + 1) * 4);
    int* cursor = (int*)alloc((size_t)NN * 4);
    int* bsum = (int*)alloc(512 * 4);
    int* boff = (int*)alloc(512 * 4);
    int* edge_src = (int*)alloc((size_t)NE * 4);
    float* bufA = (float*)alloc((size_t)NN * 256 * 4);
    float* bufB = (float*)alloc((size_t)NN * 256 * 4);
    (void)ws_size; (void)in_sizes; (void)n_in; (void)out_size;

    // zero the two count arrays (covers alignment gap between them)
    hipMemsetAsync(cnt_out, 0, (size_t)((char*)cnt_in - (char*)cnt_out) + (size_t)NN * 4, stream);

    k_hist<<<NE / 256, 256, 0, stream>>>(src, dst, cnt_out, cnt_in);
    k_deg<<<NB, 256, 0, stream>>>(cnt_out, cnt_in, deg_out_inv, deg_in_inv);
    k_scan1<<<NB, 256, 0, stream>>>(cnt_in, row_start, bsum);
    k_scan2<<<1, 512, 0, stream>>>(bsum, boff, NB);
    k_scan3<<<NB, 256, 0, stream>>>(row_start, cursor, boff);
    k_scatter<<<NE / 256, 256, 0, stream>>>(src, dst, cursor, edge_src);

    // layer 1: aggregate feat (D=128), then GEMM 128->256 + bias + deg_in, then LN+PReLU
    k_agg<128, false><<<NN / 4, 256, 0, stream>>>(feat, edge_src, row_start, deg_out_inv, nullptr, nullptr, bufA);
    k_gemm<128, 256, true><<<NN / 16, 256, 0, stream>>>(bufA, W1, b1, deg_in_inv, bufB);
    k_ln<<<NN / 4, 256, 0, stream>>>(bufB, g1, be1, a1);

    // layer 2: aggregate h1 (D=256), GEMM 256->256, LN+PReLU
    k_agg<256, false><<<NN / 4, 256, 0, stream>>>(bufB, edge_src, row_start, deg_out_inv, nullptr, nullptr, bufA);
    k_gemm<256, 256, true><<<NN / 16, 256, 0, stream>>>(bufA, W2, b2, deg_in_inv, bufB);
    k_ln<<<NN / 4, 256, 0, stream>>>(bufB, g2, be2, a2);

    // layer 3 (no LN/act): GEMM first (256->128), then aggregate (D=128) with fused
    // bias+deg_in epilogue straight into d_out
    k_gemm<256, 128, false><<<NN / 16, 256, 0, stream>>>(bufB, W3, nullptr, nullptr, bufA);
    k_agg<128, true><<<NN / 4, 256, 0, stream>>>(bufA, edge_src, row_start, deg_out_inv, deg_in_inv, b3, (float*)d_out);
}

// Round 2
// 1258.232 us; speedup vs baseline: 2.0280x; 2.0280x over previous
//
#include <hip/hip_runtime.h>
#include <cstdint>
#include <cstddef>

static constexpr int NN = 100000;   // nodes
static constexpr int NE = 1600000;  // edges
static constexpr int NB = (NN + 255) / 256;  // 391 scan blocks

typedef __attribute__((ext_vector_type(8))) short short8;   // 8 bf16 (4 VGPRs)
typedef __attribute__((ext_vector_type(4))) float f32x4;    // MFMA C/D frag

// ---------------- degree histogram ----------------
__global__ __launch_bounds__(256) void k_hist(const int* __restrict__ src, const int* __restrict__ dst,
                                              int* __restrict__ cnt_out, int* __restrict__ cnt_in) {
    int e = blockIdx.x * 256 + threadIdx.x;
    if (e < NE) {
        atomicAdd(&cnt_out[src[e]], 1);
        atomicAdd(&cnt_in[dst[e]], 1);
    }
}

__global__ __launch_bounds__(256) void k_deg(const int* __restrict__ cnt_out, const int* __restrict__ cnt_in,
                                             float* __restrict__ dout, float* __restrict__ din) {
    int i = blockIdx.x * 256 + threadIdx.x;
    if (i < NN) {
        dout[i] = rsqrtf(fmaxf((float)cnt_out[i], 1.0f));
        din[i]  = rsqrtf(fmaxf((float)cnt_in[i], 1.0f));
    }
}

// ---------------- 3-kernel exclusive scan of cnt_in -> row_start ----------------
__global__ __launch_bounds__(256) void k_scan1(const int* __restrict__ cnt, int* __restrict__ excl,
                                               int* __restrict__ bsum) {
    __shared__ int sd[256];
    int i = blockIdx.x * 256 + threadIdx.x;
    int v = (i < NN) ? cnt[i] : 0;
    sd[threadIdx.x] = v;
    __syncthreads();
    #pragma unroll
    for (int off = 1; off < 256; off <<= 1) {
        int t = (threadIdx.x >= off) ? sd[threadIdx.x - off] : 0;
        __syncthreads();
        sd[threadIdx.x] += t;
        __syncthreads();
    }
    if (i < NN) excl[i] = sd[threadIdx.x] - v;       // exclusive within block
    if (threadIdx.x == 255) bsum[blockIdx.x] = sd[255];
}

__global__ __launch_bounds__(512) void k_scan2(const int* __restrict__ bsum, int* __restrict__ boff, int nb) {
    __shared__ int sd[512];
    int v = ((int)threadIdx.x < nb) ? bsum[threadIdx.x] : 0;
    sd[threadIdx.x] = v;
    __syncthreads();
    #pragma unroll
    for (int off = 1; off < 512; off <<= 1) {
        int t = (threadIdx.x >= off) ? sd[threadIdx.x - off] : 0;
        __syncthreads();
        sd[threadIdx.x] += t;
        __syncthreads();
    }
    if ((int)threadIdx.x < nb) boff[threadIdx.x] = sd[threadIdx.x] - v;  // exclusive
}

__global__ __launch_bounds__(256) void k_scan3(int* __restrict__ row_start, int* __restrict__ cursor,
                                               const int* __restrict__ boff) {
    int i = blockIdx.x * 256 + threadIdx.x;
    if (i < NN) {
        int rs = row_start[i] + boff[blockIdx.x];
        row_start[i] = rs;
        cursor[i] = rs;
    }
    if (i == 0) row_start[NN] = NE;
}

// ---------------- counting-sort edges by dst ----------------
__global__ __launch_bounds__(256) void k_scatter(const int* __restrict__ src, const int* __restrict__ dst,
                                                 int* __restrict__ cursor, int* __restrict__ edge_src) {
    int e = blockIdx.x * 256 + threadIdx.x;
    if (e < NE) {
        int p = atomicAdd(&cursor[dst[e]], 1);
        edge_src[p] = src[e];
    }
}

// ---------------- pull aggregation: one wave per dst node ----------------
template <int D, bool FINAL>
__global__ __launch_bounds__(256) void k_agg(const float* __restrict__ x, const int* __restrict__ edge_src,
                                             const int* __restrict__ row_start,
                                             const float* __restrict__ deg_out_inv,
                                             const float* __restrict__ deg_in_inv,
                                             const float* __restrict__ bias,
                                             float* __restrict__ out) {
    constexpr int VEC = D / 64;  // 2 for D=128, 4 for D=256
    int node = blockIdx.x * 4 + (threadIdx.x >> 6);
    int lane = threadIdx.x & 63;
    int beg = row_start[node];
    int end = row_start[node + 1];
    float acc[VEC];
    #pragma unroll
    for (int v = 0; v < VEC; ++v) acc[v] = 0.0f;
    const float* xb = x + (size_t)lane * VEC;
    if (beg < end) {
        int s_next = edge_src[beg];
        for (int i = beg; i < end; ++i) {
            int s = s_next;
            s_next = edge_src[min(i + 1, end - 1)];   // prefetch next edge id
            float w = deg_out_inv[s];
            if constexpr (VEC == 4) {
                float4 val = *(const float4*)(xb + (size_t)s * D);
                acc[0] = fmaf(w, val.x, acc[0]);
                acc[1] = fmaf(w, val.y, acc[1]);
                acc[2] = fmaf(w, val.z, acc[2]);
                acc[3] = fmaf(w, val.w, acc[3]);
            } else {
                float2 val = *(const float2*)(xb + (size_t)s * D);
                acc[0] = fmaf(w, val.x, acc[0]);
                acc[1] = fmaf(w, val.y, acc[1]);
            }
        }
    }
    float* o = out + (size_t)node * D + lane * VEC;
    if constexpr (FINAL) {
        float dv = deg_in_inv[node];
        #pragma unroll
        for (int v = 0; v < VEC; ++v) o[v] = (acc[v] + bias[lane * VEC + v]) * dv;
    } else {
        #pragma unroll
        for (int v = 0; v < VEC; ++v) o[v] = acc[v];
    }
}

// ---------------- split-bf16 helpers (hi = truncate, lo = residual truncated) ----------------
__device__ inline void split_bf(const float4& p, const float4& q, short8& hi, short8& lo) {
    float x[8] = {p.x, p.y, p.z, p.w, q.x, q.y, q.z, q.w};
    uint32_t hu[8], lu[8];
    #pragma unroll
    for (int i = 0; i < 8; ++i) {
        uint32_t u = __float_as_uint(x[i]);
        hu[i] = u & 0xffff0000u;
        float lf = x[i] - __uint_as_float(hu[i]);
        lu[i] = __float_as_uint(lf);
    }
    union { short8 s; uint32_t u[4]; } H, L;
    #pragma unroll
    for (int i = 0; i < 4; ++i) {
        H.u[i] = (hu[2 * i] >> 16) | hu[2 * i + 1];
        L.u[i] = (lu[2 * i] >> 16) | (lu[2 * i + 1] & 0xffff0000u);
    }
    hi = H.s;
    lo = L.s;
}

// ---------------- pack W[K x M] fp32 -> B-fragment-ordered bf16 hi/lo planes ----------------
// layout: plane[tile = kc*NT+nt][lane][j] where element j = W[kc*32 + (lane>>4)*8 + j][nt*16 + (lane&15)]
template <int K, int M>
__global__ __launch_bounds__(256) void k_packW(const float* __restrict__ W, ushort* __restrict__ out) {
    constexpr int NT = M / 16, KC = K / 32;
    constexpr int TOT = KC * NT * 64;        // threads
    constexpr int WTOT = KC * NT * 512;      // elements per plane
    int idx = blockIdx.x * 256 + threadIdx.x;
    if (idx >= TOT) return;
    int lane = idx & 63;
    int tile = idx >> 6;
    int nt = tile % NT, kc = tile / NT;
    int col = nt * 16 + (lane & 15);
    int kbase = kc * 32 + (lane >> 4) * 8;
    size_t o = (size_t)tile * 512 + lane * 8;
    #pragma unroll
    for (int j = 0; j < 8; ++j) {
        float w = W[(size_t)(kbase + j) * M + col];
        uint32_t u = __float_as_uint(w);
        uint32_t hu = u & 0xffff0000u;
        float lf = w - __uint_as_float(hu);
        out[o + j] = (ushort)(u >> 16);
        out[o + WTOT + j] = (ushort)(__float_as_uint(lf) >> 16);
    }
}

// ---------------- split-bf16 MFMA GEMM: out[N x M] = A[N x K] @ W + epilogue ----------------
// one wave per 16 rows; A read fp32 and split in-register; W pre-packed hi/lo planes
template <int K, int M, bool EPI>
__global__ __launch_bounds__(256) void k_gemm_mfma(const float* __restrict__ A,
                                                   const ushort* __restrict__ Wp,
                                                   const float* __restrict__ bias,
                                                   const float* __restrict__ deg_in_inv,
                                                   float* __restrict__ out) {
    constexpr int NT = M / 16;
    constexpr int KC = K / 32;
    constexpr int WTOT = KC * NT * 512;
    int lane = threadIdx.x & 63;
    int wave = threadIdx.x >> 6;
    int m = lane & 15;
    int quad = lane >> 4;
    int row0 = (blockIdx.x * 4 + wave) * 16;
    const float* arow = A + (size_t)(row0 + m) * K + quad * 8;
    f32x4 acc[NT];
    #pragma unroll
    for (int t = 0; t < NT; ++t) acc[t] = (f32x4){0.f, 0.f, 0.f, 0.f};
    for (int kc = 0; kc < KC; ++kc) {
        float4 p = *(const float4*)(arow + kc * 32);
        float4 q = *(const float4*)(arow + kc * 32 + 4);
        short8 ah, al;
        split_bf(p, q, ah, al);
        const ushort* wbase = Wp + (size_t)(kc * NT) * 512 + lane * 8;
        #pragma unroll
        for (int t = 0; t < NT; ++t) {
            short8 bh = *(const short8*)(wbase + t * 512);
            short8 bl = *(const short8*)(wbase + WTOT + t * 512);
            acc[t] = __builtin_amdgcn_mfma_f32_16x16x32_bf16(ah, bh, acc[t], 0, 0, 0);
            acc[t] = __builtin_amdgcn_mfma_f32_16x16x32_bf16(ah, bl, acc[t], 0, 0, 0);
            acc[t] = __builtin_amdgcn_mfma_f32_16x16x32_bf16(al, bh, acc[t], 0, 0, 0);
        }
    }
    // D layout: col = lane&15 (=m), row = quad*4 + reg
    #pragma unroll
    for (int r = 0; r < 4; ++r) {
        int row = row0 + quad * 4 + r;
        if (row < NN) {
            float dv = 1.0f;
            if constexpr (EPI) dv = deg_in_inv[row];
            #pragma unroll
            for (int t = 0; t < NT; ++t) {
                float v = acc[t][r];
                if constexpr (EPI) v = (v + bias[t * 16 + m]) * dv;
                out[(size_t)row * M + t * 16 + m] = v;
            }
        }
    }
}

// ---------------- LayerNorm + PReLU, in place, one wave per row (D=256) ----------------
__global__ __launch_bounds__(256) void k_ln(float* __restrict__ h, const float* __restrict__ g,
                                            const float* __restrict__ be, const float* __restrict__ a) {
    int row = blockIdx.x * 4 + (threadIdx.x >> 6);
    int lane = threadIdx.x & 63;
    float* p = h + (size_t)row * 256 + lane * 4;
    float4 v = *(const float4*)p;
    float s = v.x + v.y + v.z + v.w;
    float q = v.x * v.x + v.y * v.y + v.z * v.z + v.w * v.w;
    #pragma unroll
    for (int off = 32; off > 0; off >>= 1) {
        s += __shfl_down(s, off);
        q += __shfl_down(q, off);
    }
    s = __shfl(s, 0);
    q = __shfl(q, 0);
    float mu = s * (1.0f / 256.0f);
    float var = q * (1.0f / 256.0f) - mu * mu;
    float rs = rsqrtf(var + 1e-5f);
    float alpha = a[0];
    float4 gv = *(const float4*)(g + lane * 4);
    float4 bv = *(const float4*)(be + lane * 4);
    float o0 = gv.x * (v.x - mu) * rs + bv.x; o0 = (o0 >= 0.0f) ? o0 : alpha * o0;
    float o1 = gv.y * (v.y - mu) * rs + bv.y; o1 = (o1 >= 0.0f) ? o1 : alpha * o1;
    float o2 = gv.z * (v.z - mu) * rs + bv.z; o2 = (o2 >= 0.0f) ? o2 : alpha * o2;
    float o3 = gv.w * (v.w - mu) * rs + bv.w; o3 = (o3 >= 0.0f) ? o3 : alpha * o3;
    *(float4*)p = make_float4(o0, o1, o2, o3);
}

extern "C" void kernel_launch(void* const* d_in, const int* in_sizes, int n_in,
                              void* d_out, int out_size, void* d_ws, size_t ws_size,
                              hipStream_t stream) {
    const float* feat = (const float*)d_in[0];
    const float* W1 = (const float*)d_in[1];
    const float* b1 = (const float*)d_in[2];
    const float* g1 = (const float*)d_in[3];
    const float* be1 = (const float*)d_in[4];
    const float* a1 = (const float*)d_in[5];
    const float* W2 = (const float*)d_in[6];
    const float* b2 = (const float*)d_in[7];
    const float* g2 = (const float*)d_in[8];
    const float* be2 = (const float*)d_in[9];
    const float* a2 = (const float*)d_in[10];
    const float* W3 = (const float*)d_in[11];
    const float* b3 = (const float*)d_in[12];
    const int* src = (const int*)d_in[13];
    const int* dst = (const int*)d_in[14];

    char* ws = (char*)d_ws;
    size_t off = 0;
    auto alloc = [&](size_t bytes) -> void* {
        off = (off + 511) & ~(size_t)511;
        void* p = ws + off;
        off += bytes;
        return p;
    };
    constexpr int NP = 100032;  // NN padded to 64-row granularity for GEMM tiles
    int* cnt_out = (int*)alloc((size_t)NN * 4);
    int* cnt_in = (int*)alloc((size_t)NN * 4);
    float* deg_out_inv = (float*)alloc((size_t)NN * 4);
    float* deg_in_inv = (float*)alloc((size_t)NN * 4);
    int* row_start = (int*)alloc((size_t)(NN + 1) * 4);
    int* cursor = (int*)alloc((size_t)NN * 4);
    int* bsum = (int*)alloc(512 * 4);
    int* boff = (int*)alloc(512 * 4);
    int* edge_src = (int*)alloc((size_t)NE * 4);
    ushort* Wp1 = (ushort*)alloc((size_t)2 * 4 * 16 * 512 * 2);   // K=128,M=256: 2 planes
    ushort* Wp2 = (ushort*)alloc((size_t)2 * 8 * 16 * 512 * 2);   // K=256,M=256
    ushort* Wp3 = (ushort*)alloc((size_t)2 * 8 * 8 * 512 * 2);    // K=256,M=128
    float* bufA = (float*)alloc((size_t)NP * 256 * 4);
    float* bufB = (float*)alloc((size_t)NP * 256 * 4);
    (void)ws_size; (void)in_sizes; (void)n_in; (void)out_size;

    // zero the two count arrays (covers alignment gap between them)
    hipMemsetAsync(cnt_out, 0, (size_t)((char*)cnt_in - (char*)cnt_out) + (size_t)NN * 4, stream);

    // graph structure + degrees (int atomics only)
    k_hist<<<NE / 256, 256, 0, stream>>>(src, dst, cnt_out, cnt_in);
    k_deg<<<NB, 256, 0, stream>>>(cnt_out, cnt_in, deg_out_inv, deg_in_inv);
    k_scan1<<<NB, 256, 0, stream>>>(cnt_in, row_start, bsum);
    k_scan2<<<1, 512, 0, stream>>>(bsum, boff, NB);
    k_scan3<<<NB, 256, 0, stream>>>(row_start, cursor, boff);
    k_scatter<<<NE / 256, 256, 0, stream>>>(src, dst, cursor, edge_src);

    // pack weights into MFMA B-fragment order (hi/lo bf16 planes)
    k_packW<128, 256><<<16, 256, 0, stream>>>(W1, Wp1);
    k_packW<256, 256><<<32, 256, 0, stream>>>(W2, Wp2);
    k_packW<256, 128><<<16, 256, 0, stream>>>(W3, Wp3);

    constexpr int GG = NP / 64;  // 1563 GEMM blocks (4 waves x 16 rows)

    // layer 1: aggregate feat (D=128) -> GEMM 128->256 (+bias,*deg_in) -> LN+PReLU
    k_agg<128, false><<<NN / 4, 256, 0, stream>>>(feat, edge_src, row_start, deg_out_inv, nullptr, nullptr, bufA);
    k_gemm_mfma<128, 256, true><<<GG, 256, 0, stream>>>(bufA, Wp1, b1, deg_in_inv, bufB);
    k_ln<<<NN / 4, 256, 0, stream>>>(bufB, g1, be1, a1);

    // layer 2: aggregate h1 (D=256) -> GEMM 256->256 -> LN+PReLU
    k_agg<256, false><<<NN / 4, 256, 0, stream>>>(bufB, edge_src, row_start, deg_out_inv, nullptr, nullptr, bufA);
    k_gemm_mfma<256, 256, true><<<GG, 256, 0, stream>>>(bufA, Wp2, b2, deg_in_inv, bufB);
    k_ln<<<NN / 4, 256, 0, stream>>>(bufB, g2, be2, a2);

    // layer 3 (no LN/act): GEMM first (256->128), then aggregate (D=128) with fused
    // bias+deg_in epilogue straight into d_out
    k_gemm_mfma<256, 128, false><<<GG, 256, 0, stream>>>(bufB, Wp3, nullptr, nullptr, bufA);
    k_agg<128, true><<<NN / 4, 256, 0, stream>>>(bufA, edge_src, row_start, deg_out_inv, deg_in_inv, b3, (float*)d_out);
}

// Round 3
// 1119.719 us; speedup vs baseline: 2.2788x; 1.1237x over previous
//
#include <hip/hip_runtime.h>
#include <cstdint>
#include <cstddef>

static constexpr int NN = 100000;   // nodes
static constexpr int NE = 1600000;  // edges
static constexpr int NB = (NN + 255) / 256;  // 391 scan blocks
static constexpr int NP = 100032;   // NN padded to 64-row GEMM granularity

typedef __attribute__((ext_vector_type(8))) short short8;             // 8 bf16 (4 VGPRs)
typedef __attribute__((ext_vector_type(8))) unsigned short ushort8;   // 16B bf16 chunk
typedef __attribute__((ext_vector_type(4))) float f32x4;              // MFMA C/D frag

__device__ inline ushort bf16_rtn(float x) {
    uint32_t u = __float_as_uint(x);
    uint32_t r = u + 0x7fffu + ((u >> 16) & 1u);   // round-to-nearest-even
    return (ushort)(r >> 16);
}
__device__ inline float bf16_to_f(ushort u) {
    return __uint_as_float((uint32_t)u << 16);
}

// ---------------- degree histogram ----------------
__global__ __launch_bounds__(256) void k_hist(const int* __restrict__ src, const int* __restrict__ dst,
                                              int* __restrict__ cnt_out, int* __restrict__ cnt_in) {
    int e = blockIdx.x * 256 + threadIdx.x;
    if (e < NE) {
        atomicAdd(&cnt_out[src[e]], 1);
        atomicAdd(&cnt_in[dst[e]], 1);
    }
}

__global__ __launch_bounds__(256) void k_deg(const int* __restrict__ cnt_out, const int* __restrict__ cnt_in,
                                             float* __restrict__ dout, float* __restrict__ din) {
    int i = blockIdx.x * 256 + threadIdx.x;
    if (i < NN) {
        dout[i] = rsqrtf(fmaxf((float)cnt_out[i], 1.0f));
        din[i]  = rsqrtf(fmaxf((float)cnt_in[i], 1.0f));
    }
}

// ---------------- 3-kernel exclusive scan of cnt_in -> row_start ----------------
__global__ __launch_bounds__(256) void k_scan1(const int* __restrict__ cnt, int* __restrict__ excl,
                                               int* __restrict__ bsum) {
    __shared__ int sd[256];
    int i = blockIdx.x * 256 + threadIdx.x;
    int v = (i < NN) ? cnt[i] : 0;
    sd[threadIdx.x] = v;
    __syncthreads();
    #pragma unroll
    for (int off = 1; off < 256; off <<= 1) {
        int t = (threadIdx.x >= off) ? sd[threadIdx.x - off] : 0;
        __syncthreads();
        sd[threadIdx.x] += t;
        __syncthreads();
    }
    if (i < NN) excl[i] = sd[threadIdx.x] - v;
    if (threadIdx.x == 255) bsum[blockIdx.x] = sd[255];
}

__global__ __launch_bounds__(512) void k_scan2(const int* __restrict__ bsum, int* __restrict__ boff, int nb) {
    __shared__ int sd[512];
    int v = ((int)threadIdx.x < nb) ? bsum[threadIdx.x] : 0;
    sd[threadIdx.x] = v;
    __syncthreads();
    #pragma unroll
    for (int off = 1; off < 512; off <<= 1) {
        int t = (threadIdx.x >= off) ? sd[threadIdx.x - off] : 0;
        __syncthreads();
        sd[threadIdx.x] += t;
        __syncthreads();
    }
    if ((int)threadIdx.x < nb) boff[threadIdx.x] = sd[threadIdx.x] - v;
}

__global__ __launch_bounds__(256) void k_scan3(int* __restrict__ row_start, int* __restrict__ cursor,
                                               const int* __restrict__ boff) {
    int i = blockIdx.x * 256 + threadIdx.x;
    if (i < NN) {
        int rs = row_start[i] + boff[blockIdx.x];
        row_start[i] = rs;
        cursor[i] = rs;
    }
    if (i == 0) row_start[NN] = NE;
}

// ---------------- counting-sort edges by dst ----------------
__global__ __launch_bounds__(256) void k_scatter(const int* __restrict__ src, const int* __restrict__ dst,
                                                 int* __restrict__ cursor, int* __restrict__ edge_src) {
    int e = blockIdx.x * 256 + threadIdx.x;
    if (e < NE) {
        int p = atomicAdd(&cursor[dst[e]], 1);
        edge_src[p] = src[e];
    }
}

// ---------------- feat fp32 -> bf16 with deg_out_inv folded ----------------
__global__ __launch_bounds__(256) void k_cvt(const float* __restrict__ feat,
                                             const float* __restrict__ deg_out_inv,
                                             ushort* __restrict__ out) {
    int idx = blockIdx.x * 256 + threadIdx.x;            // one float4 per thread
    if (idx >= NN * 32) return;                          // NN*128/4
    float4 v = *(const float4*)(feat + (size_t)idx * 4);
    float w = deg_out_inv[idx >> 5];                     // (idx*4)/128
    ushort4 o;
    o.x = bf16_rtn(v.x * w);
    o.y = bf16_rtn(v.y * w);
    o.z = bf16_rtn(v.z * w);
    o.w = bf16_rtn(v.w * w);
    *(ushort4*)(out + (size_t)idx * 4) = o;
}

// ---------------- pull aggregation over bf16 rows: one wave per dst node ----------------
// x rows already include deg_out_inv fold. acc in fp32.
// FINAL: out_f[n] = (acc + bias) * deg_in_inv[n]  (fp32 d_out); else out_b = bf16(acc)
template <int D, bool FINAL>
__global__ __launch_bounds__(256) void k_agg(const ushort* __restrict__ x, const int* __restrict__ edge_src,
                                             const int* __restrict__ row_start,
                                             const float* __restrict__ deg_in_inv,
                                             const float* __restrict__ bias,
                                             ushort* __restrict__ out_b,
                                             float* __restrict__ out_f) {
    constexpr int VEC = D / 64;  // 2 for D=128, 4 for D=256
    int node = blockIdx.x * 4 + (threadIdx.x >> 6);
    int lane = threadIdx.x & 63;
    int beg = row_start[node];
    int end = row_start[node + 1];
    float acc[VEC];
    #pragma unroll
    for (int v = 0; v < VEC; ++v) acc[v] = 0.0f;
    const ushort* xb = x + (size_t)lane * VEC;
    if (beg < end) {
        int s_next = edge_src[beg];
        for (int i = beg; i < end; ++i) {
            int s = s_next;
            s_next = edge_src[min(i + 1, end - 1)];   // prefetch next edge id
            if constexpr (VEC == 4) {
                ushort4 u = *(const ushort4*)(xb + (size_t)s * D);
                acc[0] += bf16_to_f(u.x);
                acc[1] += bf16_to_f(u.y);
                acc[2] += bf16_to_f(u.z);
                acc[3] += bf16_to_f(u.w);
            } else {
                ushort2 u = *(const ushort2*)(xb + (size_t)s * D);
                acc[0] += bf16_to_f(u.x);
                acc[1] += bf16_to_f(u.y);
            }
        }
    }
    if constexpr (FINAL) {
        float dv = deg_in_inv[node];
        float* o = out_f + (size_t)node * D + lane * VEC;
        #pragma unroll
        for (int v = 0; v < VEC; ++v) o[v] = (acc[v] + bias[lane * VEC + v]) * dv;
    } else {
        ushort* o = out_b + (size_t)node * D + lane * VEC;
        if constexpr (VEC == 4) {
            ushort4 u;
            u.x = bf16_rtn(acc[0]); u.y = bf16_rtn(acc[1]);
            u.z = bf16_rtn(acc[2]); u.w = bf16_rtn(acc[3]);
            *(ushort4*)o = u;
        } else {
            ushort2 u;
            u.x = bf16_rtn(acc[0]); u.y = bf16_rtn(acc[1]);
            *(ushort2*)o = u;
        }
    }
}

// ---------------- pack W[K x M] fp32 -> B-fragment-ordered bf16 hi/lo planes ----------------
template <int K, int M>
__global__ __launch_bounds__(256) void k_packW(const float* __restrict__ W, ushort* __restrict__ out) {
    constexpr int NT = M / 16, KC = K / 32;
    constexpr int TOT = KC * NT * 64;        // threads
    constexpr int WTOT = KC * NT * 512;      // elements per plane
    int idx = blockIdx.x * 256 + threadIdx.x;
    if (idx >= TOT) return;
    int lane = idx & 63;
    int tile = idx >> 6;
    int nt = tile % NT, kc = tile / NT;
    int col = nt * 16 + (lane & 15);
    int kbase = kc * 32 + (lane >> 4) * 8;
    size_t o = (size_t)tile * 512 + lane * 8;
    #pragma unroll
    for (int j = 0; j < 8; ++j) {
        float w = W[(size_t)(kbase + j) * M + col];
        uint32_t u = __float_as_uint(w);
        uint32_t hu = u & 0xffff0000u;
        float lf = w - __uint_as_float(hu);
        out[o + j] = (ushort)(u >> 16);
        out[o + WTOT + j] = (ushort)(__float_as_uint(lf) >> 16);
    }
}

// ---------------- bf16 MFMA GEMM with fused epilogue ----------------
// A [NP x K] bf16 row-major (deg_out already folded upstream where needed).
// W split hi/lo -> 2 MFMAs per tile recover full W precision.
// MODE 0: out = bf16(A@W)                        (layer-3 pre-aggregation)
// MODE 1: out = bf16(prelu(LN((A@W+b)*deg_in)) * deg_out)  (layers 1,2)
template <int K, int M, int MODE>
__global__ __launch_bounds__(256) void k_gemm_mfma(const ushort* __restrict__ A,
                                                   const ushort* __restrict__ Wp,
                                                   const float* __restrict__ bias,
                                                   const float* __restrict__ deg_in_inv,
                                                   const float* __restrict__ deg_out_inv,
                                                   const float* __restrict__ g,
                                                   const float* __restrict__ be,
                                                   const float* __restrict__ a,
                                                   ushort* __restrict__ out) {
    constexpr int NT = M / 16;
    constexpr int KC = K / 32;
    constexpr int WTOT = KC * NT * 512;
    constexpr int LROW = M + 8;              // padded LDS row (ushorts) to spread banks
    __shared__ ushort sbuf[4 * 16 * LROW];
    int lane = threadIdx.x & 63;
    int wave = threadIdx.x >> 6;
    int m = lane & 15;
    int quad = lane >> 4;
    int rowb = (blockIdx.x * 4 + wave) * 16;
    const ushort* arow = A + (size_t)(rowb + m) * K + quad * 8;
    f32x4 acc[NT];
    #pragma unroll
    for (int t = 0; t < NT; ++t) acc[t] = (f32x4){0.f, 0.f, 0.f, 0.f};
    for (int kc = 0; kc < KC; ++kc) {
        short8 av = *(const short8*)(arow + kc * 32);
        const ushort* wbase = Wp + (size_t)(kc * NT) * 512 + lane * 8;
        #pragma unroll
        for (int t = 0; t < NT; ++t) {
            short8 bh = *(const short8*)(wbase + t * 512);
            short8 bl = *(const short8*)(wbase + WTOT + t * 512);
            acc[t] = __builtin_amdgcn_mfma_f32_16x16x32_bf16(av, bh, acc[t], 0, 0, 0);
            acc[t] = __builtin_amdgcn_mfma_f32_16x16x32_bf16(av, bl, acc[t], 0, 0, 0);
        }
    }
    // D layout: col = t*16 + m, row = rowb + quad*4 + r
    ushort* sw = sbuf + wave * 16 * LROW;
    if constexpr (MODE == 1) {
        float bia[NT];
        #pragma unroll
        for (int t = 0; t < NT; ++t) bia[t] = bias[t * 16 + m];
        float din[4], fold[4];
        #pragma unroll
        for (int r = 0; r < 4; ++r) {
            int row = rowb + quad * 4 + r;
            din[r] = deg_in_inv[row];
            fold[r] = deg_out_inv[row];
        }
        // pre-LN value
        #pragma unroll
        for (int t = 0; t < NT; ++t)
            #pragma unroll
            for (int r = 0; r < 4; ++r)
                acc[t][r] = (acc[t][r] + bia[t]) * din[r];
        // row mean/var across the 16 lanes of this quad (each lane holds NT cols)
        float s[4], q[4];
        #pragma unroll
        for (int r = 0; r < 4; ++r) { s[r] = 0.f; q[r] = 0.f; }
        #pragma unroll
        for (int t = 0; t < NT; ++t)
            #pragma unroll
            for (int r = 0; r < 4; ++r) {
                s[r] += acc[t][r];
                q[r] += acc[t][r] * acc[t][r];
            }
        #pragma unroll
        for (int w = 1; w < 16; w <<= 1)
            #pragma unroll
            for (int r = 0; r < 4; ++r) {
                s[r] += __shfl_xor(s[r], w);
                q[r] += __shfl_xor(q[r], w);
            }
        float mu[4], rs[4];
        #pragma unroll
        for (int r = 0; r < 4; ++r) {
            mu[r] = s[r] * (1.0f / M);
            float var = q[r] * (1.0f / M) - mu[r] * mu[r];
            rs[r] = rsqrtf(var + 1e-5f);
        }
        float alpha = a[0];
        #pragma unroll
        for (int t = 0; t < NT; ++t) {
            float gv = g[t * 16 + m];
            float bev = be[t * 16 + m];
            #pragma unroll
            for (int r = 0; r < 4; ++r) {
                float v = gv * (acc[t][r] - mu[r]) * rs[r] + bev;
                v = (v >= 0.0f) ? v : alpha * v;
                v *= fold[r];                 // next layer's deg_out_inv
                sw[(quad * 4 + r) * LROW + t * 16 + m] = bf16_rtn(v);
            }
        }
    } else {
        #pragma unroll
        for (int t = 0; t < NT; ++t)
            #pragma unroll
            for (int r = 0; r < 4; ++r)
                sw[(quad * 4 + r) * LROW + t * 16 + m] = bf16_rtn(acc[t][r]);
    }
    __syncthreads();
    // coalesced bf16 write-back: lane covers CNT contiguous ushorts of this wave's 16xM block
    constexpr int CNT = 16 * M / 64;          // 64 (M=256) or 32 (M=128)
    int row = (lane * CNT) / M;
    int col0 = (lane * CNT) % M;
    const ushort* rsrc = sbuf + wave * 16 * LROW + row * LROW + col0;
    ushort* gdst = out + (size_t)(rowb + row) * M + col0;
    #pragma unroll
    for (int j = 0; j < CNT / 8; ++j) {
        ushort8 v = *(const ushort8*)(rsrc + j * 8);
        *(ushort8*)(gdst + j * 8) = v;
    }
}

extern "C" void kernel_launch(void* const* d_in, const int* in_sizes, int n_in,
                              void* d_out, int out_size, void* d_ws, size_t ws_size,
                              hipStream_t stream) {
    const float* feat = (const float*)d_in[0];
    const float* W1 = (const float*)d_in[1];
    const float* b1 = (const float*)d_in[2];
    const float* g1 = (const float*)d_in[3];
    const float* be1 = (const float*)d_in[4];
    const float* a1 = (const float*)d_in[5];
    const float* W2 = (const float*)d_in[6];
    const float* b2 = (const float*)d_in[7];
    const float* g2 = (const float*)d_in[8];
    const float* be2 = (const float*)d_in[9];
    const float* a2 = (const float*)d_in[10];
    const float* W3 = (const float*)d_in[11];
    const float* b3 = (const float*)d_in[12];
    const int* src = (const int*)d_in[13];
    const int* dst = (const int*)d_in[14];

    char* ws = (char*)d_ws;
    size_t off = 0;
    auto alloc = [&](size_t bytes) -> void* {
        off = (off + 511) & ~(size_t)511;
        void* p = ws + off;
        off += bytes;
        return p;
    };
    int* cnt_out = (int*)alloc((size_t)NN * 4);
    int* cnt_in = (int*)alloc((size_t)NN * 4);
    float* deg_out_inv = (float*)alloc((size_t)NP * 4);
    float* deg_in_inv = (float*)alloc((size_t)NP * 4);
    int* row_start = (int*)alloc((size_t)(NN + 1) * 4);
    int* cursor = (int*)alloc((size_t)NN * 4);
    int* bsum = (int*)alloc(512 * 4);
    int* boff = (int*)alloc(512 * 4);
    int* edge_src = (int*)alloc((size_t)NE * 4);
    ushort* Wp1 = (ushort*)alloc((size_t)2 * 4 * 16 * 512 * 2);   // K=128,M=256 hi/lo
    ushort* Wp2 = (ushort*)alloc((size_t)2 * 8 * 16 * 512 * 2);   // K=256,M=256
    ushort* Wp3 = (ushort*)alloc((size_t)2 * 8 * 8 * 512 * 2);    // K=256,M=128
    ushort* featb = (ushort*)alloc((size_t)NP * 128 * 2);   // feat*deg_out, bf16
    ushort* aggb  = (ushort*)alloc((size_t)NP * 256 * 2);   // aggregation output (reused)
    ushort* hb    = (ushort*)alloc((size_t)NP * 256 * 2);   // h*deg_out, bf16 (reused)
    ushort* yb    = (ushort*)alloc((size_t)NP * 128 * 2);   // layer-3 GEMM output
    (void)ws_size; (void)in_sizes; (void)n_in; (void)out_size;

    // zero the two count arrays (covers alignment gap between them)
    hipMemsetAsync(cnt_out, 0, (size_t)((char*)cnt_in - (char*)cnt_out) + (size_t)NN * 4, stream);

    // graph structure + degrees (int atomics only)
    k_hist<<<NE / 256, 256, 0, stream>>>(src, dst, cnt_out, cnt_in);
    k_deg<<<NB, 256, 0, stream>>>(cnt_out, cnt_in, deg_out_inv, deg_in_inv);
    k_scan1<<<NB, 256, 0, stream>>>(cnt_in, row_start, bsum);
    k_scan2<<<1, 512, 0, stream>>>(bsum, boff, NB);
    k_scan3<<<NB, 256, 0, stream>>>(row_start, cursor, boff);
    k_scatter<<<NE / 256, 256, 0, stream>>>(src, dst, cursor, edge_src);

    // weights -> MFMA fragment order (hi/lo planes); feat -> bf16 with deg_out fold
    k_packW<128, 256><<<16, 256, 0, stream>>>(W1, Wp1);
    k_packW<256, 256><<<32, 256, 0, stream>>>(W2, Wp2);
    k_packW<256, 128><<<16, 256, 0, stream>>>(W3, Wp3);
    k_cvt<<<(NN * 32 + 255) / 256, 256, 0, stream>>>(feat, deg_out_inv, featb);

    constexpr int GG = NP / 64;  // 1563 GEMM blocks (4 waves x 16 rows)

    // layer 1: agg(feat*deg_out) -> GEMM 128->256 [+b1,*deg_in,LN,PReLU,*deg_out] -> h1b
    k_agg<128, false><<<NN / 4, 256, 0, stream>>>(featb, edge_src, row_start, nullptr, nullptr, aggb, nullptr);
    k_gemm_mfma<128, 256, 1><<<GG, 256, 0, stream>>>(aggb, Wp1, b1, deg_in_inv, deg_out_inv, g1, be1, a1, hb);

    // layer 2: agg(h1*deg_out) -> GEMM 256->256 [epilogue] -> h2b (h2*deg_out)
    k_agg<256, false><<<NN / 4, 256, 0, stream>>>(hb, edge_src, row_start, nullptr, nullptr, aggb, nullptr);
    k_gemm_mfma<256, 256, 1><<<GG, 256, 0, stream>>>(aggb, Wp2, b2, deg_in_inv, deg_out_inv, g2, be2, a2, hb);

    // layer 3: GEMM (h2*deg_out)@W3 -> yb, then agg(yb) with (+b3)*deg_in into d_out
    k_gemm_mfma<256, 128, 0><<<GG, 256, 0, stream>>>(hb, Wp3, nullptr, nullptr, nullptr, nullptr, nullptr, nullptr, yb);
    k_agg<128, true><<<NN / 4, 256, 0, stream>>>(yb, edge_src, row_start, deg_in_inv, b3, nullptr, (float*)d_out);
}

// Round 4
// 866.232 us; speedup vs baseline: 2.9457x; 1.2926x over previous
//
#include <hip/hip_runtime.h>
#include <cstdint>
#include <cstddef>

static constexpr int NN = 100000;   // nodes
static constexpr int NE = 1600000;  // edges
static constexpr int NB = (NN + 255) / 256;  // 391 scan blocks
static constexpr int NP = 100032;   // NN padded to 64-row GEMM granularity

typedef __attribute__((ext_vector_type(8))) short short8;             // 8 bf16 (4 VGPRs)
typedef __attribute__((ext_vector_type(8))) unsigned short ushort8;   // 16B bf16 chunk
typedef __attribute__((ext_vector_type(4))) float f32x4;              // MFMA C/D frag

__device__ inline ushort bf16_rtn(float x) {
    uint32_t u = __float_as_uint(x);
    uint32_t r = u + 0x7fffu + ((u >> 16) & 1u);   // round-to-nearest-even
    return (ushort)(r >> 16);
}
__device__ inline float bf16_to_f(ushort u) {
    return __uint_as_float((uint32_t)u << 16);
}

// ---------------- degree histogram ----------------
__global__ __launch_bounds__(256) void k_hist(const int* __restrict__ src, const int* __restrict__ dst,
                                              int* __restrict__ cnt_out, int* __restrict__ cnt_in) {
    int e = blockIdx.x * 256 + threadIdx.x;
    if (e < NE) {
        atomicAdd(&cnt_out[src[e]], 1);
        atomicAdd(&cnt_in[dst[e]], 1);
    }
}

// ---------------- fused: degree rsqrt + block-level scan of cnt_in ----------------
__global__ __launch_bounds__(256) void k_deg_scan(const int* __restrict__ cnt_out, const int* __restrict__ cnt_in,
                                                  float* __restrict__ dout, float* __restrict__ din,
                                                  int* __restrict__ excl, int* __restrict__ bsum) {
    __shared__ int sd[256];
    int i = blockIdx.x * 256 + threadIdx.x;
    int v = (i < NN) ? cnt_in[i] : 0;
    if (i < NN) {
        dout[i] = rsqrtf(fmaxf((float)cnt_out[i], 1.0f));
        din[i]  = rsqrtf(fmaxf((float)v, 1.0f));
    }
    sd[threadIdx.x] = v;
    __syncthreads();
    #pragma unroll
    for (int off = 1; off < 256; off <<= 1) {
        int t = (threadIdx.x >= off) ? sd[threadIdx.x - off] : 0;
        __syncthreads();
        sd[threadIdx.x] += t;
        __syncthreads();
    }
    if (i < NN) excl[i] = sd[threadIdx.x] - v;
    if (threadIdx.x == 255) bsum[blockIdx.x] = sd[255];
}

__global__ __launch_bounds__(512) void k_scan2(const int* __restrict__ bsum, int* __restrict__ boff, int nb) {
    __shared__ int sd[512];
    int v = ((int)threadIdx.x < nb) ? bsum[threadIdx.x] : 0;
    sd[threadIdx.x] = v;
    __syncthreads();
    #pragma unroll
    for (int off = 1; off < 512; off <<= 1) {
        int t = (threadIdx.x >= off) ? sd[threadIdx.x - off] : 0;
        __syncthreads();
        sd[threadIdx.x] += t;
        __syncthreads();
    }
    if ((int)threadIdx.x < nb) boff[threadIdx.x] = sd[threadIdx.x] - v;
}

__global__ __launch_bounds__(256) void k_scan3(int* __restrict__ row_start, int* __restrict__ cursor,
                                               const int* __restrict__ boff) {
    int i = blockIdx.x * 256 + threadIdx.x;
    if (i < NN) {
        int rs = row_start[i] + boff[blockIdx.x];
        row_start[i] = rs;
        cursor[i] = rs;
    }
    if (i == 0) row_start[NN] = NE;
}

// ---------------- counting-sort edges by dst ----------------
__global__ __launch_bounds__(256) void k_scatter(const int* __restrict__ src, const int* __restrict__ dst,
                                                 int* __restrict__ cursor, int* __restrict__ edge_src) {
    int e = blockIdx.x * 256 + threadIdx.x;
    if (e < NE) {
        int p = atomicAdd(&cursor[dst[e]], 1);
        edge_src[p] = src[e];
    }
}

// ---------------- feat fp32 -> bf16 with deg_out_inv folded ----------------
__global__ __launch_bounds__(256) void k_cvt(const float* __restrict__ feat,
                                             const float* __restrict__ deg_out_inv,
                                             ushort* __restrict__ out) {
    int idx = blockIdx.x * 256 + threadIdx.x;            // one float4 per thread
    if (idx >= NN * 32) return;                          // NN*128/4
    float4 v = *(const float4*)(feat + (size_t)idx * 4);
    float w = deg_out_inv[idx >> 5];                     // (idx*4)/128
    ushort4 o;
    o.x = bf16_rtn(v.x * w);
    o.y = bf16_rtn(v.y * w);
    o.z = bf16_rtn(v.z * w);
    o.w = bf16_rtn(v.w * w);
    *(ushort4*)(out + (size_t)idx * 4) = o;
}

// ---------------- pull aggregation over bf16 rows ----------------
// One wave per dst node; the two 32-lane halves gather DIFFERENT edges' rows
// (16B/lane for D=256, 8B/lane for D=128), 4 gathers in flight (8 edges),
// clamped indices + 0/1 weights give a uniform loop with no remainder.
// x rows already include the deg_out_inv fold; acc in fp32.
template <int D, bool FINAL>
__global__ __launch_bounds__(256) void k_agg(const ushort* __restrict__ x, const int* __restrict__ edge_src,
                                             const int* __restrict__ row_start,
                                             const float* __restrict__ deg_in_inv,
                                             const float* __restrict__ bias,
                                             ushort* __restrict__ out_b,
                                             float* __restrict__ out_f) {
    constexpr int VEC = D / 32;               // cols per lane within a half-wave row
    int node = blockIdx.x * 4 + (threadIdx.x >> 6);
    int lane = threadIdx.x & 63;
    int half = lane >> 5;
    int l5 = lane & 31;
    int beg = row_start[node];
    int end = row_start[node + 1];
    float acc[VEC];
    #pragma unroll
    for (int v = 0; v < VEC; ++v) acc[v] = 0.0f;
    const ushort* xb = x + (size_t)l5 * VEC;
    for (int i = beg; i < end; i += 8) {
        int id[4];
        float w[4];
        #pragma unroll
        for (int u = 0; u < 4; ++u) {
            int e = i + 2 * u + half;
            id[u] = edge_src[min(e, end - 1)];
            w[u] = (e < end) ? 1.0f : 0.0f;
        }
        #pragma unroll
        for (int u = 0; u < 4; ++u) {
            if constexpr (VEC == 8) {
                ushort8 val = *(const ushort8*)(xb + (size_t)id[u] * D);
                #pragma unroll
                for (int v = 0; v < 8; ++v) acc[v] = fmaf(w[u], bf16_to_f(val[v]), acc[v]);
            } else {
                ushort4 val = *(const ushort4*)(xb + (size_t)id[u] * D);
                acc[0] = fmaf(w[u], bf16_to_f(val.x), acc[0]);
                acc[1] = fmaf(w[u], bf16_to_f(val.y), acc[1]);
                acc[2] = fmaf(w[u], bf16_to_f(val.z), acc[2]);
                acc[3] = fmaf(w[u], bf16_to_f(val.w), acc[3]);
            }
        }
    }
    // combine the two half-wave partial sums
    #pragma unroll
    for (int v = 0; v < VEC; ++v) acc[v] += __shfl_xor(acc[v], 32);
    if (half == 0) {
        if constexpr (FINAL) {
            float dv = deg_in_inv[node];
            float4 bv = *(const float4*)(bias + l5 * 4);
            float4 o4;
            o4.x = (acc[0] + bv.x) * dv;
            o4.y = (acc[1] + bv.y) * dv;
            o4.z = (acc[2] + bv.z) * dv;
            o4.w = (acc[3] + bv.w) * dv;
            *(float4*)(out_f + (size_t)node * D + l5 * 4) = o4;
        } else {
            ushort* o = out_b + (size_t)node * D + l5 * VEC;
            if constexpr (VEC == 8) {
                ushort8 uv;
                #pragma unroll
                for (int v = 0; v < 8; ++v) uv[v] = bf16_rtn(acc[v]);
                *(ushort8*)o = uv;
            } else {
                ushort4 uv;
                uv.x = bf16_rtn(acc[0]); uv.y = bf16_rtn(acc[1]);
                uv.z = bf16_rtn(acc[2]); uv.w = bf16_rtn(acc[3]);
                *(ushort4*)o = uv;
            }
        }
    }
}

// ---------------- pack W[K x M] fp32 -> B-fragment-ordered bf16 hi/lo planes ----------------
template <int K, int M>
__device__ inline void packW_dev(const float* __restrict__ W, ushort* __restrict__ out, int blk) {
    constexpr int NT = M / 16, KC = K / 32;
    constexpr int WTOT = KC * NT * 512;      // elements per plane
    int idx = blk * 256 + (int)threadIdx.x;
    int lane = idx & 63;
    int tile = idx >> 6;
    int nt = tile % NT, kc = tile / NT;
    int col = nt * 16 + (lane & 15);
    int kbase = kc * 32 + (lane >> 4) * 8;
    size_t o = (size_t)tile * 512 + lane * 8;
    #pragma unroll
    for (int j = 0; j < 8; ++j) {
        float w = W[(size_t)(kbase + j) * M + col];
        uint32_t u = __float_as_uint(w);
        uint32_t hu = u & 0xffff0000u;
        float lf = w - __uint_as_float(hu);
        out[o + j] = (ushort)(u >> 16);
        out[o + WTOT + j] = (ushort)(__float_as_uint(lf) >> 16);
    }
}

__global__ __launch_bounds__(256) void k_packAll(const float* __restrict__ W1, ushort* __restrict__ o1,
                                                 const float* __restrict__ W2, ushort* __restrict__ o2,
                                                 const float* __restrict__ W3, ushort* __restrict__ o3) {
    int b = blockIdx.x;
    if (b < 16) packW_dev<128, 256>(W1, o1, b);            // 4*16 tiles
    else if (b < 48) packW_dev<256, 256>(W2, o2, b - 16);  // 8*16 tiles
    else packW_dev<256, 128>(W3, o3, b - 48);              // 8*8 tiles
}

// ---------------- bf16 MFMA GEMM with fused epilogue ----------------
// MODE 0: out = bf16(A@W)                                  (layer-3 pre-aggregation)
// MODE 1: out = bf16(prelu(LN((A@W+b)*deg_in)) * deg_out)  (layers 1,2)
template <int K, int M, int MODE>
__global__ __launch_bounds__(256) void k_gemm_mfma(const ushort* __restrict__ A,
                                                   const ushort* __restrict__ Wp,
                                                   const float* __restrict__ bias,
                                                   const float* __restrict__ deg_in_inv,
                                                   const float* __restrict__ deg_out_inv,
                                                   const float* __restrict__ g,
                                                   const float* __restrict__ be,
                                                   const float* __restrict__ a,
                                                   ushort* __restrict__ out) {
    constexpr int NT = M / 16;
    constexpr int KC = K / 32;
    constexpr int WTOT = KC * NT * 512;
    constexpr int LROW = M + 8;              // padded LDS row (ushorts)
    __shared__ ushort sbuf[4 * 16 * LROW];
    int lane = threadIdx.x & 63;
    int wave = threadIdx.x >> 6;
    int m = lane & 15;
    int quad = lane >> 4;
    int rowb = (blockIdx.x * 4 + wave) * 16;
    const ushort* arow = A + (size_t)(rowb + m) * K + quad * 8;
    f32x4 acc[NT];
    #pragma unroll
    for (int t = 0; t < NT; ++t) acc[t] = (f32x4){0.f, 0.f, 0.f, 0.f};
    for (int kc = 0; kc < KC; ++kc) {
        short8 av = *(const short8*)(arow + kc * 32);
        const ushort* wbase = Wp + (size_t)(kc * NT) * 512 + lane * 8;
        #pragma unroll
        for (int t = 0; t < NT; ++t) {
            short8 bh = *(const short8*)(wbase + t * 512);
            short8 bl = *(const short8*)(wbase + WTOT + t * 512);
            acc[t] = __builtin_amdgcn_mfma_f32_16x16x32_bf16(av, bh, acc[t], 0, 0, 0);
            acc[t] = __builtin_amdgcn_mfma_f32_16x16x32_bf16(av, bl, acc[t], 0, 0, 0);
        }
    }
    // D layout: col = t*16 + m, row = rowb + quad*4 + r
    ushort* sw = sbuf + wave * 16 * LROW;
    if constexpr (MODE == 1) {
        float bia[NT];
        #pragma unroll
        for (int t = 0; t < NT; ++t) bia[t] = bias[t * 16 + m];
        float din[4], fold[4];
        #pragma unroll
        for (int r = 0; r < 4; ++r) {
            int row = rowb + quad * 4 + r;
            din[r] = deg_in_inv[row];
            fold[r] = deg_out_inv[row];
        }
        #pragma unroll
        for (int t = 0; t < NT; ++t)
            #pragma unroll
            for (int r = 0; r < 4; ++r)
                acc[t][r] = (acc[t][r] + bia[t]) * din[r];
        float s[4], q[4];
        #pragma unroll
        for (int r = 0; r < 4; ++r) { s[r] = 0.f; q[r] = 0.f; }
        #pragma unroll
        for (int t = 0; t < NT; ++t)
            #pragma unroll
            for (int r = 0; r < 4; ++r) {
                s[r] += acc[t][r];
                q[r] += acc[t][r] * acc[t][r];
            }
        #pragma unroll
        for (int w = 1; w < 16; w <<= 1)
            #pragma unroll
            for (int r = 0; r < 4; ++r) {
                s[r] += __shfl_xor(s[r], w);
                q[r] += __shfl_xor(q[r], w);
            }
        float mu[4], rs[4];
        #pragma unroll
        for (int r = 0; r < 4; ++r) {
            mu[r] = s[r] * (1.0f / M);
            float var = q[r] * (1.0f / M) - mu[r] * mu[r];
            rs[r] = rsqrtf(var + 1e-5f);
        }
        float alpha = a[0];
        #pragma unroll
        for (int t = 0; t < NT; ++t) {
            float gv = g[t * 16 + m];
            float bev = be[t * 16 + m];
            #pragma unroll
            for (int r = 0; r < 4; ++r) {
                float v = gv * (acc[t][r] - mu[r]) * rs[r] + bev;
                v = (v >= 0.0f) ? v : alpha * v;
                v *= fold[r];
                sw[(quad * 4 + r) * LROW + t * 16 + m] = bf16_rtn(v);
            }
        }
    } else {
        #pragma unroll
        for (int t = 0; t < NT; ++t)
            #pragma unroll
            for (int r = 0; r < 4; ++r)
                sw[(quad * 4 + r) * LROW + t * 16 + m] = bf16_rtn(acc[t][r]);
    }
    __syncthreads();
    constexpr int CNT = 16 * M / 64;          // contiguous ushorts per lane
    int row = (lane * CNT) / M;
    int col0 = (lane * CNT) % M;
    const ushort* rsrc = sbuf + wave * 16 * LROW + row * LROW + col0;
    ushort* gdst = out + (size_t)(rowb + row) * M + col0;
    #pragma unroll
    for (int j = 0; j < CNT / 8; ++j) {
        ushort8 v = *(const ushort8*)(rsrc + j * 8);
        *(ushort8*)(gdst + j * 8) = v;
    }
}

extern "C" void kernel_launch(void* const* d_in, const int* in_sizes, int n_in,
                              void* d_out, int out_size, void* d_ws, size_t ws_size,
                              hipStream_t stream) {
    const float* feat = (const float*)d_in[0];
    const float* W1 = (const float*)d_in[1];
    const float* b1 = (const float*)d_in[2];
    const float* g1 = (const float*)d_in[3];
    const float* be1 = (const float*)d_in[4];
    const float* a1 = (const float*)d_in[5];
    const float* W2 = (const float*)d_in[6];
    const float* b2 = (const float*)d_in[7];
    const float* g2 = (const float*)d_in[8];
    const float* be2 = (const float*)d_in[9];
    const float* a2 = (const float*)d_in[10];
    const float* W3 = (const float*)d_in[11];
    const float* b3 = (const float*)d_in[12];
    const int* src = (const int*)d_in[13];
    const int* dst = (const int*)d_in[14];

    char* ws = (char*)d_ws;
    size_t off = 0;
    auto alloc = [&](size_t bytes) -> void* {
        off = (off + 511) & ~(size_t)511;
        void* p = ws + off;
        off += bytes;
        return p;
    };
    int* cnt_out = (int*)alloc((size_t)NN * 4);
    int* cnt_in = (int*)alloc((size_t)NN * 4);
    float* deg_out_inv = (float*)alloc((size_t)NP * 4);
    float* deg_in_inv = (float*)alloc((size_t)NP * 4);
    int* row_start = (int*)alloc((size_t)(NN + 1) * 4);
    int* cursor = (int*)alloc((size_t)NN * 4);
    int* bsum = (int*)alloc(512 * 4);
    int* boff = (int*)alloc(512 * 4);
    int* edge_src = (int*)alloc((size_t)NE * 4);
    ushort* Wp1 = (ushort*)alloc((size_t)2 * 4 * 16 * 512 * 2);   // K=128,M=256 hi/lo
    ushort* Wp2 = (ushort*)alloc((size_t)2 * 8 * 16 * 512 * 2);   // K=256,M=256
    ushort* Wp3 = (ushort*)alloc((size_t)2 * 8 * 8 * 512 * 2);    // K=256,M=128
    ushort* featb = (ushort*)alloc((size_t)NP * 128 * 2);   // feat*deg_out, bf16
    ushort* aggb  = (ushort*)alloc((size_t)NP * 256 * 2);   // aggregation output (reused)
    ushort* hb    = (ushort*)alloc((size_t)NP * 256 * 2);   // h*deg_out, bf16 (reused)
    ushort* yb    = (ushort*)alloc((size_t)NP * 128 * 2);   // layer-3 GEMM output
    (void)ws_size; (void)in_sizes; (void)n_in; (void)out_size;

    hipMemsetAsync(cnt_out, 0, (size_t)((char*)cnt_in - (char*)cnt_out) + (size_t)NN * 4, stream);

    // graph structure + degrees (int atomics only)
    k_hist<<<NE / 256, 256, 0, stream>>>(src, dst, cnt_out, cnt_in);
    k_deg_scan<<<NB, 256, 0, stream>>>(cnt_out, cnt_in, deg_out_inv, deg_in_inv, row_start, bsum);
    k_scan2<<<1, 512, 0, stream>>>(bsum, boff, NB);
    k_scan3<<<NB, 256, 0, stream>>>(row_start, cursor, boff);
    k_scatter<<<NE / 256, 256, 0, stream>>>(src, dst, cursor, edge_src);

    // weights -> MFMA fragment order (hi/lo planes); feat -> bf16 with deg_out fold
    k_packAll<<<64, 256, 0, stream>>>(W1, Wp1, W2, Wp2, W3, Wp3);
    k_cvt<<<(NN * 32 + 255) / 256, 256, 0, stream>>>(feat, deg_out_inv, featb);

    constexpr int GG = NP / 64;  // 1563 GEMM blocks (4 waves x 16 rows)

    // layer 1: agg(feat*deg_out) -> GEMM 128->256 [+b1,*deg_in,LN,PReLU,*deg_out] -> h1b
    k_agg<128, false><<<NN / 4, 256, 0, stream>>>(featb, edge_src, row_start, nullptr, nullptr, aggb, nullptr);
    k_gemm_mfma<128, 256, 1><<<GG, 256, 0, stream>>>(aggb, Wp1, b1, deg_in_inv, deg_out_inv, g1, be1, a1, hb);

    // layer 2: agg(h1*deg_out) -> GEMM 256->256 [epilogue] -> h2b (h2*deg_out)
    k_agg<256, false><<<NN / 4, 256, 0, stream>>>(hb, edge_src, row_start, nullptr, nullptr, aggb, nullptr);
    k_gemm_mfma<256, 256, 1><<<GG, 256, 0, stream>>>(aggb, Wp2, b2, deg_in_inv, deg_out_inv, g2, be2, a2, hb);

    // layer 3: GEMM (h2*deg_out)@W3 -> yb, then agg(yb) with (+b3)*deg_in into d_out
    k_gemm_mfma<256, 128, 0><<<GG, 256, 0, stream>>>(hb, Wp3, nullptr, nullptr, nullptr, nullptr, nullptr, nullptr, yb);
    k_agg<128, true><<<NN / 4, 256, 0, stream>>>(yb, edge_src, row_start, deg_in_inv, b3, nullptr, (float*)d_out);
}

// Round 5
// 775.739 us; speedup vs baseline: 3.2893x; 1.1167x over previous
//
#include <hip/hip_runtime.h>
#include <cstdint>
#include <cstddef>

static constexpr int NN = 100000;   // nodes
static constexpr int NE = 1600000;  // edges
static constexpr int NB = (NN + 255) / 256;  // 391 scan blocks
static constexpr int NP = 100096;   // NN padded to 128-row GEMM granularity

typedef __attribute__((ext_vector_type(8))) short short8;             // 8 bf16 (4 VGPRs)
typedef __attribute__((ext_vector_type(8))) unsigned short ushort8;   // 16B bf16 chunk
typedef __attribute__((ext_vector_type(4))) float f32x4;              // MFMA C/D frag

__device__ inline ushort bf16_rtn(float x) {
    uint32_t u = __float_as_uint(x);
    uint32_t r = u + 0x7fffu + ((u >> 16) & 1u);   // round-to-nearest-even
    return (ushort)(r >> 16);
}
__device__ inline float bf16_to_f(ushort u) {
    return __uint_as_float((uint32_t)u << 16);
}

// ---------------- degree histogram ----------------
__global__ __launch_bounds__(256) void k_hist(const int* __restrict__ src, const int* __restrict__ dst,
                                              int* __restrict__ cnt_out, int* __restrict__ cnt_in) {
    int e = blockIdx.x * 256 + threadIdx.x;
    if (e < NE) {
        atomicAdd(&cnt_out[src[e]], 1);
        atomicAdd(&cnt_in[dst[e]], 1);
    }
}

// ---------------- fused: degree rsqrt + block-level scan of cnt_in ----------------
__global__ __launch_bounds__(256) void k_deg_scan(const int* __restrict__ cnt_out, const int* __restrict__ cnt_in,
                                                  float* __restrict__ dout, float* __restrict__ din,
                                                  int* __restrict__ excl, int* __restrict__ bsum) {
    __shared__ int sd[256];
    int i = blockIdx.x * 256 + threadIdx.x;
    int v = (i < NN) ? cnt_in[i] : 0;
    if (i < NN) {
        dout[i] = rsqrtf(fmaxf((float)cnt_out[i], 1.0f));
        din[i]  = rsqrtf(fmaxf((float)v, 1.0f));
    }
    sd[threadIdx.x] = v;
    __syncthreads();
    #pragma unroll
    for (int off = 1; off < 256; off <<= 1) {
        int t = (threadIdx.x >= off) ? sd[threadIdx.x - off] : 0;
        __syncthreads();
        sd[threadIdx.x] += t;
        __syncthreads();
    }
    if (i < NN) excl[i] = sd[threadIdx.x] - v;
    if (threadIdx.x == 255) bsum[blockIdx.x] = sd[255];
}

__global__ __launch_bounds__(512) void k_scan2(const int* __restrict__ bsum, int* __restrict__ boff, int nb) {
    __shared__ int sd[512];
    int v = ((int)threadIdx.x < nb) ? bsum[threadIdx.x] : 0;
    sd[threadIdx.x] = v;
    __syncthreads();
    #pragma unroll
    for (int off = 1; off < 512; off <<= 1) {
        int t = (threadIdx.x >= off) ? sd[threadIdx.x - off] : 0;
        __syncthreads();
        sd[threadIdx.x] += t;
        __syncthreads();
    }
    if ((int)threadIdx.x < nb) boff[threadIdx.x] = sd[threadIdx.x] - v;
}

__global__ __launch_bounds__(256) void k_scan3(int* __restrict__ row_start, int* __restrict__ cursor,
                                               const int* __restrict__ boff) {
    int i = blockIdx.x * 256 + threadIdx.x;
    if (i < NN) {
        int rs = row_start[i] + boff[blockIdx.x];
        row_start[i] = rs;
        cursor[i] = rs;
    }
    if (i == 0) row_start[NN] = NE;
}

// ---------------- counting-sort edges by dst ----------------
__global__ __launch_bounds__(256) void k_scatter(const int* __restrict__ src, const int* __restrict__ dst,
                                                 int* __restrict__ cursor, int* __restrict__ edge_src) {
    int e = blockIdx.x * 256 + threadIdx.x;
    if (e < NE) {
        int p = atomicAdd(&cursor[dst[e]], 1);
        edge_src[p] = src[e];
    }
}

// ---------------- feat fp32 -> bf16 with deg_out_inv folded ----------------
__global__ __launch_bounds__(256) void k_cvt(const float* __restrict__ feat,
                                             const float* __restrict__ deg_out_inv,
                                             ushort* __restrict__ out) {
    int idx = blockIdx.x * 256 + threadIdx.x;            // one float4 per thread
    if (idx >= NN * 32) return;                          // NN*128/4
    float4 v = *(const float4*)(feat + (size_t)idx * 4);
    float w = deg_out_inv[idx >> 5];                     // (idx*4)/128
    ushort4 o;
    o.x = bf16_rtn(v.x * w);
    o.y = bf16_rtn(v.y * w);
    o.z = bf16_rtn(v.z * w);
    o.w = bf16_rtn(v.w * w);
    *(ushort4*)(out + (size_t)idx * 4) = o;
}

// ---------------- pull aggregation over bf16 rows ----------------
// One wave per dst node; the two 32-lane halves gather DIFFERENT edges' rows,
// 4 gathers in flight (8 edges), clamped indices + 0/1 weights.
template <int D, bool FINAL>
__global__ __launch_bounds__(256) void k_agg(const ushort* __restrict__ x, const int* __restrict__ edge_src,
                                             const int* __restrict__ row_start,
                                             const float* __restrict__ deg_in_inv,
                                             const float* __restrict__ bias,
                                             ushort* __restrict__ out_b,
                                             float* __restrict__ out_f) {
    constexpr int VEC = D / 32;               // cols per lane within a half-wave row
    int node = blockIdx.x * 4 + (threadIdx.x >> 6);
    int lane = threadIdx.x & 63;
    int half = lane >> 5;
    int l5 = lane & 31;
    int beg = row_start[node];
    int end = row_start[node + 1];
    float acc[VEC];
    #pragma unroll
    for (int v = 0; v < VEC; ++v) acc[v] = 0.0f;
    const ushort* xb = x + (size_t)l5 * VEC;
    for (int i = beg; i < end; i += 8) {
        int id[4];
        float w[4];
        #pragma unroll
        for (int u = 0; u < 4; ++u) {
            int e = i + 2 * u + half;
            id[u] = edge_src[min(e, end - 1)];
            w[u] = (e < end) ? 1.0f : 0.0f;
        }
        #pragma unroll
        for (int u = 0; u < 4; ++u) {
            if constexpr (VEC == 8) {
                ushort8 val = *(const ushort8*)(xb + (size_t)id[u] * D);
                #pragma unroll
                for (int v = 0; v < 8; ++v) acc[v] = fmaf(w[u], bf16_to_f(val[v]), acc[v]);
            } else {
                ushort4 val = *(const ushort4*)(xb + (size_t)id[u] * D);
                acc[0] = fmaf(w[u], bf16_to_f(val.x), acc[0]);
                acc[1] = fmaf(w[u], bf16_to_f(val.y), acc[1]);
                acc[2] = fmaf(w[u], bf16_to_f(val.z), acc[2]);
                acc[3] = fmaf(w[u], bf16_to_f(val.w), acc[3]);
            }
        }
    }
    #pragma unroll
    for (int v = 0; v < VEC; ++v) acc[v] += __shfl_xor(acc[v], 32);
    if (half == 0) {
        if constexpr (FINAL) {
            float dv = deg_in_inv[node];
            float4 bv = *(const float4*)(bias + l5 * 4);
            float4 o4;
            o4.x = (acc[0] + bv.x) * dv;
            o4.y = (acc[1] + bv.y) * dv;
            o4.z = (acc[2] + bv.z) * dv;
            o4.w = (acc[3] + bv.w) * dv;
            *(float4*)(out_f + (size_t)node * D + l5 * 4) = o4;
        } else {
            ushort* o = out_b + (size_t)node * D + l5 * VEC;
            if constexpr (VEC == 8) {
                ushort8 uv;
                #pragma unroll
                for (int v = 0; v < 8; ++v) uv[v] = bf16_rtn(acc[v]);
                *(ushort8*)o = uv;
            } else {
                ushort4 uv;
                uv.x = bf16_rtn(acc[0]); uv.y = bf16_rtn(acc[1]);
                uv.z = bf16_rtn(acc[2]); uv.w = bf16_rtn(acc[3]);
                *(ushort4*)o = uv;
            }
        }
    }
}

// ---------------- pack W[K x M] fp32 -> B-fragment-ordered bf16 hi/lo planes ----------------
template <int K, int M>
__device__ inline void packW_dev(const float* __restrict__ W, ushort* __restrict__ out, int blk) {
    constexpr int NT = M / 16, KC = K / 32;
    constexpr int WTOT = KC * NT * 512;      // elements per plane
    int idx = blk * 256 + (int)threadIdx.x;
    int lane = idx & 63;
    int tile = idx >> 6;
    int nt = tile % NT, kc = tile / NT;
    int col = nt * 16 + (lane & 15);
    int kbase = kc * 32 + (lane >> 4) * 8;
    size_t o = (size_t)tile * 512 + lane * 8;
    #pragma unroll
    for (int j = 0; j < 8; ++j) {
        float w = W[(size_t)(kbase + j) * M + col];
        uint32_t u = __float_as_uint(w);
        uint32_t hu = u & 0xffff0000u;
        float lf = w - __uint_as_float(hu);
        out[o + j] = (ushort)(u >> 16);
        out[o + WTOT + j] = (ushort)(__float_as_uint(lf) >> 16);
    }
}

__global__ __launch_bounds__(256) void k_packAll(const float* __restrict__ W1, ushort* __restrict__ o1,
                                                 const float* __restrict__ W2, ushort* __restrict__ o2,
                                                 const float* __restrict__ W3, ushort* __restrict__ o3) {
    int b = blockIdx.x;
    if (b < 16) packW_dev<128, 256>(W1, o1, b);            // 4*16 tiles
    else if (b < 48) packW_dev<256, 256>(W2, o2, b - 16);  // 8*16 tiles
    else packW_dev<256, 128>(W3, o3, b - 48);              // 8*8 tiles
}

// ---------------- bf16 MFMA GEMM, 64x64 wave tiles, fused epilogue ----------------
// Wave tile: 64 rows x 64 cols (4 row-frags x 4 col-tiles); each B-frag load
// feeds 4 MFMAs, each A-frag load feeds 8 -> 32 MFMAs per 12 loads per kc.
// M=256: block = 64 rows x 256 cols (4 col-wave groups, cross-wave LDS LN).
// M=128: block = 128 rows x 128 cols (2x2 wave grid).
// MODE 0: out = bf16(A@W)
// MODE 1: out = bf16(prelu(LN((A@W+b)*deg_in)) * deg_out)   [requires M=256]
template <int K, int M, int MODE>
__global__ __launch_bounds__(256) void k_gemm_mfma(const ushort* __restrict__ A,
                                                   const ushort* __restrict__ Wp,
                                                   const float* __restrict__ bias,
                                                   const float* __restrict__ deg_in_inv,
                                                   const float* __restrict__ deg_out_inv,
                                                   const float* __restrict__ g,
                                                   const float* __restrict__ be,
                                                   const float* __restrict__ a,
                                                   ushort* __restrict__ out) {
    constexpr int NT = M / 16;
    constexpr int KC = K / 32;
    constexpr int WTOT = KC * NT * 512;
    constexpr int COLW = M / 64;          // waves across cols (4 for M=256, 2 for M=128)
    constexpr int ROWW = 4 / COLW;        // row groups per block
    constexpr int BROWS = 64 * ROWW;      // rows per block
    constexpr int LROW = M + 8;           // padded LDS row (ushorts)
    __shared__ ushort sbuf[BROWS * LROW];
    __shared__ float sredS[4][64];
    __shared__ float sredQ[4][64];
    __shared__ float smu[64];
    __shared__ float srs[64];

    int lane = threadIdx.x & 63;
    int wave = threadIdx.x >> 6;
    int cw = wave % COLW;                 // col group
    int rw = wave / COLW;                 // row group (0 when M=256)
    int m = lane & 15;
    int quad = lane >> 4;
    int rowb = blockIdx.x * BROWS + rw * 64;

    f32x4 acc[4][4];
    #pragma unroll
    for (int rf = 0; rf < 4; ++rf)
        #pragma unroll
        for (int ct = 0; ct < 4; ++ct) acc[rf][ct] = (f32x4){0.f, 0.f, 0.f, 0.f};

    const ushort* abase = A + (size_t)(rowb + m) * K + quad * 8;
    for (int kc = 0; kc < KC; ++kc) {
        short8 av[4];
        #pragma unroll
        for (int rf = 0; rf < 4; ++rf)
            av[rf] = *(const short8*)(abase + (size_t)rf * 16 * K + kc * 32);
        const ushort* wb0 = Wp + ((size_t)kc * NT + cw * 4) * 512 + lane * 8;
        #pragma unroll
        for (int ct = 0; ct < 4; ++ct) {
            short8 bh = *(const short8*)(wb0 + ct * 512);
            short8 bl = *(const short8*)(wb0 + WTOT + ct * 512);
            #pragma unroll
            for (int rf = 0; rf < 4; ++rf) {
                acc[rf][ct] = __builtin_amdgcn_mfma_f32_16x16x32_bf16(av[rf], bh, acc[rf][ct], 0, 0, 0);
                acc[rf][ct] = __builtin_amdgcn_mfma_f32_16x16x32_bf16(av[rf], bl, acc[rf][ct], 0, 0, 0);
            }
        }
    }
    // acc[rf][ct][r] holds row_local = rw*64 + rf*16 + quad*4 + r, col = cw*64 + ct*16 + m
    if constexpr (MODE == 1) {
        // bias + deg_in
        float bia[4];
        #pragma unroll
        for (int ct = 0; ct < 4; ++ct) bia[ct] = bias[cw * 64 + ct * 16 + m];
        float din[4][4], fold[4][4];
        #pragma unroll
        for (int rf = 0; rf < 4; ++rf)
            #pragma unroll
            for (int r = 0; r < 4; ++r) {
                int row = rowb + rf * 16 + quad * 4 + r;
                din[rf][r] = deg_in_inv[row];
                fold[rf][r] = deg_out_inv[row];
            }
        float s[4][4], q[4][4];
        #pragma unroll
        for (int rf = 0; rf < 4; ++rf)
            #pragma unroll
            for (int r = 0; r < 4; ++r) { s[rf][r] = 0.f; q[rf][r] = 0.f; }
        #pragma unroll
        for (int rf = 0; rf < 4; ++rf)
            #pragma unroll
            for (int ct = 0; ct < 4; ++ct)
                #pragma unroll
                for (int r = 0; r < 4; ++r) {
                    float v = (acc[rf][ct][r] + bia[ct]) * din[rf][r];
                    acc[rf][ct][r] = v;
                    s[rf][r] += v;
                    q[rf][r] += v * v;
                }
        // reduce over the 16 m-lanes of this quad -> wave partial for 64 cols
        #pragma unroll
        for (int w = 1; w < 16; w <<= 1)
            #pragma unroll
            for (int rf = 0; rf < 4; ++rf)
                #pragma unroll
                for (int r = 0; r < 4; ++r) {
                    s[rf][r] += __shfl_xor(s[rf][r], w);
                    q[rf][r] += __shfl_xor(q[rf][r], w);
                }
        if (m == 0) {
            #pragma unroll
            for (int rf = 0; rf < 4; ++rf)
                #pragma unroll
                for (int r = 0; r < 4; ++r) {
                    int rl = rf * 16 + quad * 4 + r;
                    sredS[wave][rl] = s[rf][r];
                    sredQ[wave][rl] = q[rf][r];
                }
        }
        __syncthreads();
        if (threadIdx.x < 64) {
            int rl = threadIdx.x;
            float st = sredS[0][rl] + sredS[1][rl] + sredS[2][rl] + sredS[3][rl];
            float qt = sredQ[0][rl] + sredQ[1][rl] + sredQ[2][rl] + sredQ[3][rl];
            float mu = st * (1.0f / M);
            float var = qt * (1.0f / M) - mu * mu;
            smu[rl] = mu;
            srs[rl] = rsqrtf(var + 1e-5f);
        }
        __syncthreads();
        float alpha = a[0];
        float gv[4], bev[4];
        #pragma unroll
        for (int ct = 0; ct < 4; ++ct) {
            gv[ct] = g[cw * 64 + ct * 16 + m];
            bev[ct] = be[cw * 64 + ct * 16 + m];
        }
        #pragma unroll
        for (int rf = 0; rf < 4; ++rf)
            #pragma unroll
            for (int r = 0; r < 4; ++r) {
                int rl = rf * 16 + quad * 4 + r;
                float mu = smu[rl];
                float rs = srs[rl];
                float fo = fold[rf][r];
                #pragma unroll
                for (int ct = 0; ct < 4; ++ct) {
                    float v = gv[ct] * (acc[rf][ct][r] - mu) * rs + bev[ct];
                    v = (v >= 0.0f) ? v : alpha * v;
                    v *= fo;
                    sbuf[rl * LROW + cw * 64 + ct * 16 + m] = bf16_rtn(v);
                }
            }
    } else {
        #pragma unroll
        for (int rf = 0; rf < 4; ++rf)
            #pragma unroll
            for (int ct = 0; ct < 4; ++ct)
                #pragma unroll
                for (int r = 0; r < 4; ++r)
                    sbuf[(rw * 64 + rf * 16 + quad * 4 + r) * LROW + cw * 64 + ct * 16 + m] =
                        bf16_rtn(acc[rf][ct][r]);
    }
    __syncthreads();
    // coalesced bf16 write-back: thread covers 64 contiguous ushorts of one row
    constexpr int CNT = BROWS * M / 256;        // 64 both cases
    int trow = ((int)threadIdx.x * CNT) / M;
    int tcol = ((int)threadIdx.x * CNT) % M;
    const ushort* rsrc = sbuf + trow * LROW + tcol;
    ushort* gdst = out + (size_t)(blockIdx.x * BROWS + trow) * M + tcol;
    #pragma unroll
    for (int j = 0; j < CNT / 8; ++j) {
        ushort8 v = *(const ushort8*)(rsrc + j * 8);
        *(ushort8*)(gdst + j * 8) = v;
    }
}

extern "C" void kernel_launch(void* const* d_in, const int* in_sizes, int n_in,
                              void* d_out, int out_size, void* d_ws, size_t ws_size,
                              hipStream_t stream) {
    const float* feat = (const float*)d_in[0];
    const float* W1 = (const float*)d_in[1];
    const float* b1 = (const float*)d_in[2];
    const float* g1 = (const float*)d_in[3];
    const float* be1 = (const float*)d_in[4];
    const float* a1 = (const float*)d_in[5];
    const float* W2 = (const float*)d_in[6];
    const float* b2 = (const float*)d_in[7];
    const float* g2 = (const float*)d_in[8];
    const float* be2 = (const float*)d_in[9];
    const float* a2 = (const float*)d_in[10];
    const float* W3 = (const float*)d_in[11];
    const float* b3 = (const float*)d_in[12];
    const int* src = (const int*)d_in[13];
    const int* dst = (const int*)d_in[14];

    char* ws = (char*)d_ws;
    size_t off = 0;
    auto alloc = [&](size_t bytes) -> void* {
        off = (off + 511) & ~(size_t)511;
        void* p = ws + off;
        off += bytes;
        return p;
    };
    int* cnt_out = (int*)alloc((size_t)NN * 4);
    int* cnt_in = (int*)alloc((size_t)NN * 4);
    float* deg_out_inv = (float*)alloc((size_t)NP * 4);
    float* deg_in_inv = (float*)alloc((size_t)NP * 4);
    int* row_start = (int*)alloc((size_t)(NN + 1) * 4);
    int* cursor = (int*)alloc((size_t)NN * 4);
    int* bsum = (int*)alloc(512 * 4);
    int* boff = (int*)alloc(512 * 4);
    int* edge_src = (int*)alloc((size_t)NE * 4);
    ushort* Wp1 = (ushort*)alloc((size_t)2 * 4 * 16 * 512 * 2);   // K=128,M=256 hi/lo
    ushort* Wp2 = (ushort*)alloc((size_t)2 * 8 * 16 * 512 * 2);   // K=256,M=256
    ushort* Wp3 = (ushort*)alloc((size_t)2 * 8 * 8 * 512 * 2);    // K=256,M=128
    ushort* featb = (ushort*)alloc((size_t)NP * 128 * 2);   // feat*deg_out, bf16
    ushort* aggb  = (ushort*)alloc((size_t)NP * 256 * 2);   // aggregation output (reused)
    ushort* hb    = (ushort*)alloc((size_t)NP * 256 * 2);   // h*deg_out, bf16 (reused)
    ushort* yb    = (ushort*)alloc((size_t)NP * 128 * 2);   // layer-3 GEMM output
    (void)ws_size; (void)in_sizes; (void)n_in; (void)out_size;

    hipMemsetAsync(cnt_out, 0, (size_t)((char*)cnt_in - (char*)cnt_out) + (size_t)NN * 4, stream);

    // graph structure + degrees (int atomics only)
    k_hist<<<NE / 256, 256, 0, stream>>>(src, dst, cnt_out, cnt_in);
    k_deg_scan<<<NB, 256, 0, stream>>>(cnt_out, cnt_in, deg_out_inv, deg_in_inv, row_start, bsum);
    k_scan2<<<1, 512, 0, stream>>>(bsum, boff, NB);
    k_scan3<<<NB, 256, 0, stream>>>(row_start, cursor, boff);
    k_scatter<<<NE / 256, 256, 0, stream>>>(src, dst, cursor, edge_src);

    // weights -> MFMA fragment order (hi/lo planes); feat -> bf16 with deg_out fold
    k_packAll<<<64, 256, 0, stream>>>(W1, Wp1, W2, Wp2, W3, Wp3);
    k_cvt<<<(NN * 32 + 255) / 256, 256, 0, stream>>>(feat, deg_out_inv, featb);

    // layer 1: agg(feat*deg_out) -> GEMM 128->256 [+b1,*deg_in,LN,PReLU,*deg_out] -> h1b
    k_agg<128, false><<<NN / 4, 256, 0, stream>>>(featb, edge_src, row_start, nullptr, nullptr, aggb, nullptr);
    k_gemm_mfma<128, 256, 1><<<NP / 64, 256, 0, stream>>>(aggb, Wp1, b1, deg_in_inv, deg_out_inv, g1, be1, a1, hb);

    // layer 2: agg(h1*deg_out) -> GEMM 256->256 [epilogue] -> h2b (h2*deg_out)
    k_agg<256, false><<<NN / 4, 256, 0, stream>>>(hb, edge_src, row_start, nullptr, nullptr, aggb, nullptr);
    k_gemm_mfma<256, 256, 1><<<NP / 64, 256, 0, stream>>>(aggb, Wp2, b2, deg_in_inv, deg_out_inv, g2, be2, a2, hb);

    // layer 3: GEMM (h2*deg_out)@W3 -> yb, then agg(yb) with (+b3)*deg_in into d_out
    k_gemm_mfma<256, 128, 0><<<NP / 128, 256, 0, stream>>>(hb, Wp3, nullptr, nullptr, nullptr, nullptr, nullptr, nullptr, yb);
    k_agg<128, true><<<NN / 4, 256, 0, stream>>>(yb, edge_src, row_start, deg_in_inv, b3, nullptr, (float*)d_out);
}